// Round 13
// baseline (410.173 us; speedup 1.0000x reference)
//
#include <hip/hip_runtime.h>

#define BN_EPS 1e-5f
#define KNN 20

static inline int ceildiv(int a, int b) { return (a + b - 1) / b; }

// ---- 64-bit xor-shuffle for the one-time bitonic init ----
__device__ __forceinline__ unsigned long long shflxor64(unsigned long long v, int m, int w) {
    int lo = __shfl_xor((int)(unsigned)(v & 0xffffffffull), m, w);
    int hi = __shfl_xor((int)(unsigned)(v >> 32), m, w);
    return ((unsigned long long)(unsigned)hi << 32) | (unsigned)lo;
}

// ====== stage-1 moments (Σp, Σppᵀ per chunk) + packed float4(x,y,z,|p|²) =====
__global__ void moments3_kernel(const float* __restrict__ x, int N,
                                float* __restrict__ part /*[B*4][9]*/,
                                float4* __restrict__ pk /*[B][N]*/) {
    int b = blockIdx.x;
    int chunk = blockIdx.y;          // 4 chunks of N/4
    int t = threadIdx.x;             // 256
    int n0 = chunk * (N >> 2);
    int n1 = n0 + (N >> 2);
    const float* xb = x + (size_t)b * 3 * N;
    float m[9] = {0, 0, 0, 0, 0, 0, 0, 0, 0};
    for (int n = n0 + t; n < n1; n += 256) {
        float px = xb[n], py = xb[N + n], pz = xb[2 * N + n];
        float nr = px * px + py * py + pz * pz;
        pk[(size_t)b * N + n] = make_float4(px, py, pz, nr);
        m[0] += px; m[1] += py; m[2] += pz;
        m[3] += px * px; m[4] += py * py; m[5] += pz * pz;
        m[6] += px * py; m[7] += px * pz; m[8] += py * pz;
    }
#pragma unroll
    for (int o = 32; o; o >>= 1)
#pragma unroll
        for (int i = 0; i < 9; ++i) m[i] += __shfl_down(m[i], o);
    __shared__ float red[4][9];
    if ((t & 63) == 0)
#pragma unroll
        for (int i = 0; i < 9; ++i) red[t >> 6][i] = m[i];
    __syncthreads();
    if (t == 0) {
#pragma unroll
        for (int i = 0; i < 9; ++i)
            part[(b * 4 + chunk) * 9 + i] = red[0][i] + red[1][i] + red[2][i] + red[3][i];
    }
}

// ============ KNN: 2 queries/wave, f32 scan keys, u64 bitonic init ==========
// Lean (VGPR ~18). Main loop unrolled to 128 candidates (4 sub-tiles) with one
// 20th-best refresh per iteration; stale-threshold gating is a superset of the
// exact gate (inserts only shrink the threshold), so selection stays exact.
__global__ void knn_all_kernel(const float4* __restrict__ pk, int Nstride,
                               int* __restrict__ iA, int* __restrict__ iB,
                               int* __restrict__ iC, int* __restrict__ iD,
                               int* __restrict__ iE, int* __restrict__ iF) {
    int b = blockIdx.y;
    int bx = blockIdx.x;
    int M, N; int* out; int qbase;
    if (bx < 128)      { M = 1024; N = 4096; out = iA; qbase = bx * 8; }
    else if (bx < 136) { M = 64;   N = 1024; out = iB; qbase = (bx - 128) * 8; }
    else if (bx < 168) { M = 256;  N = 1024; out = iC; qbase = (bx - 136) * 8; }
    else if (bx < 176) { M = 64;   N = 256;  out = iD; qbase = (bx - 168) * 8; }
    else if (bx < 192) { M = 128;  N = 256;  out = iE; qbase = (bx - 176) * 8; }
    else               { M = 64;   N = 128;  out = iF; qbase = (bx - 192) * 8; }
    int wave = threadIdx.x >> 6;
    int lane = threadIdx.x & 63;
    int sl = lane & 31;          // segment lane
    int half = lane >> 5;        // which query of the pair
    int q = qbase + wave * 2 + half;
    const float4* pb = pk + (size_t)b * Nstride;
    float4 qp = pb[q];

    auto dist = [&](int j) -> float {
        float4 c = pb[j];
        return qp.w + c.w - 2.f * (qp.x * c.x + qp.y * c.y + qp.z * c.z);
    };

    int up_addr = ((sl == 0) ? lane : (lane - 1)) << 2;
    int wd_addr = (19 + (half << 5)) << 2;
    int segbyte = half << 7;

    unsigned long long lk;
    {
        float d2 = dist(sl);
        unsigned u = __float_as_uint(d2);
        unsigned ok = (u & 0x80000000u) ? ~u : (u | 0x80000000u);
        lk = ((unsigned long long)ok << 32) | (unsigned)sl;
    }
#pragma unroll
    for (int size = 2; size <= 32; size <<= 1) {
#pragma unroll
        for (int stride = size >> 1; stride >= 1; stride >>= 1) {
            unsigned long long p = shflxor64(lk, stride, 32);
            bool ascend = (sl & size) == 0;
            bool low = (sl & stride) == 0;
            bool keepMin = (ascend == low);
            bool pLess = p < lk;
            lk = (keepMin == pLess) ? p : lk;
        }
    }
    unsigned okey = (unsigned)(lk >> 32);
    unsigned du = (okey & 0x80000000u) ? (okey ^ 0x80000000u) : ~okey;
    float ld = __uint_as_float(du);
    int li = (int)(unsigned)(lk & 0xffffffffull);
    float wd = __uint_as_float(__builtin_amdgcn_ds_bpermute(wd_addr, (int)__float_as_uint(ld)));

    auto insert2 = [&](float dc, int jb, unsigned long long msk) {
        unsigned mlo = (unsigned)msk, mhi = (unsigned)(msk >> 32);
        while (mlo | mhi) {
            int slo = __ffs((int)mlo) - 1;
            int shi = __ffs((int)mhi) - 1;
            int srcl = half ? shi : slo;
            int addr = ((srcl & 31) << 2) + segbyte;
            float d = __uint_as_float(__builtin_amdgcn_ds_bpermute(addr, (int)__float_as_uint(dc)));
            if (srcl < 0) d = 3.4e38f;
            int id = jb + (srcl & 31);
            float up_d = __uint_as_float(__builtin_amdgcn_ds_bpermute(up_addr, (int)__float_as_uint(ld)));
            int up_i = __builtin_amdgcn_ds_bpermute(up_addr, li);
            bool c = d < ld;
            bool cp = (sl != 0) && (d < up_d);
            ld = c ? (cp ? up_d : d) : ld;
            li = c ? (cp ? up_i : id) : li;
            mlo &= mlo - 1;
            mhi &= mhi - 1;
        }
    };

    {   // tile 1 (candidates 32..63)
        float dc = dist(32 + sl);
        unsigned long long m = __ballot(dc < wd);
        if (m) {
            insert2(dc, 32, m);
            wd = __uint_as_float(__builtin_amdgcn_ds_bpermute(wd_addr, (int)__float_as_uint(ld)));
        }
    }
    int j0 = 64;
    for (; j0 + 128 <= N; j0 += 128) {
        float dc0 = dist(j0 + sl);
        float dc1 = dist(j0 + 32 + sl);
        float dc2 = dist(j0 + 64 + sl);
        float dc3 = dist(j0 + 96 + sl);
        unsigned long long m0 = __ballot(dc0 < wd);
        unsigned long long m1 = __ballot(dc1 < wd);
        unsigned long long m2 = __ballot(dc2 < wd);
        unsigned long long m3 = __ballot(dc3 < wd);
        if (m0 | m1 | m2 | m3) {
            if (m0) insert2(dc0, j0, m0);
            if (m1) insert2(dc1, j0 + 32, m1);
            if (m2) insert2(dc2, j0 + 64, m2);
            if (m3) insert2(dc3, j0 + 96, m3);
            wd = __uint_as_float(__builtin_amdgcn_ds_bpermute(wd_addr, (int)__float_as_uint(ld)));
        }
    }
    if (j0 < N) {   // exactly 64 remaining
        float dc0 = dist(j0 + sl);
        float dc1 = dist(j0 + 32 + sl);
        unsigned long long m0 = __ballot(dc0 < wd);
        unsigned long long m1 = __ballot(dc1 < wd);
        if (m0) insert2(dc0, j0, m0);
        if (m1) insert2(dc1, j0 + 32, m1);
    }
    if (sl < KNN) out[((size_t)b * M + q) * KNN + sl] = li;
}

// ============ stage-1 pool: fused finalize1 + gather + dot + bn + lrelu ======
__global__ void pool1_kernel(const float4* __restrict__ pk, int N, const int* __restrict__ idxA,
                             const float* __restrict__ w1, const float* __restrict__ mom,
                             const float* __restrict__ g, const float* __restrict__ bb,
                             float Rinv, int nparts, float* __restrict__ out, int M) {
    __shared__ float S[9];
    __shared__ float sca[64], shb[64];
    int c = threadIdx.x;                    // 64
    int tid = threadIdx.y * 64 + c;
    if (tid < 9) {
        float s = 0.f;
        for (int bi = 0; bi < nparts; ++bi) s += mom[bi * 9 + tid];
        S[tid] = s;
    }
    __syncthreads();
    if (tid < 64) {
        float wx = w1[tid * 3], wy = w1[tid * 3 + 1], wz = w1[tid * 3 + 2];
        float mean = (wx * S[0] + wy * S[1] + wz * S[2]) * Rinv;
        float e2 = (wx * wx * S[3] + wy * wy * S[4] + wz * wz * S[5] +
                    2.f * (wx * wy * S[6] + wx * wz * S[7] + wy * wz * S[8])) * Rinv;
        float var = e2 - mean * mean;
        float a = g[tid] * rsqrtf(var + BN_EPS);
        sca[tid] = a;
        shb[tid] = bb[tid] - mean * a;
    }
    __syncthreads();
    int m = blockIdx.x * 4 + threadIdx.y;
    int b = blockIdx.y;
    const float4* pb = pk + (size_t)b * N;
    const int* ip = idxA + ((size_t)b * M + m) * KNN;
    float wx = w1[c * 3], wy = w1[c * 3 + 1], wz = w1[c * 3 + 2];
    float mx = -3.4e38f, mn = 3.4e38f;
#pragma unroll
    for (int k = 0; k < KNN; ++k) {
        float4 p = pb[ip[k]];
        float d = wx * p.x + wy * p.y + wz * p.z;
        mx = fmaxf(mx, d); mn = fminf(mn, d);
    }
    float a = sca[c];
    float v = a * (a >= 0.f ? mx : mn) + shb[c];
    out[((size_t)b * M + m) * 64 + c] = v >= 0.f ? v : 0.2f * v;
}

// ====== gather pool with bn+lrelu from scsh (min/max trick) ============
__global__ void pool_bn_kernel(const float* __restrict__ f, const int* __restrict__ idx,
                               float* __restrict__ out, int M, int Nf, int C,
                               int out_stride, int out_off, const float* __restrict__ scsh) {
    int c = threadIdx.x;                               // blockDim.x == C
    int m = blockIdx.x * blockDim.y + threadIdx.y;
    int b = blockIdx.y;
    const int* ip = idx + ((size_t)b * M + m) * KNN;
    const float* fb = f + (size_t)b * Nf * C;
    float mx = -3.4e38f, mn = 3.4e38f;
#pragma unroll
    for (int k = 0; k < KNN; ++k) {
        int j = ip[k];
        float v = fb[(size_t)j * C + c];
        mx = fmaxf(mx, v);
        mn = fminf(mn, v);
    }
    float a = scsh[c];
    float v = a * (a >= 0.f ? mx : mn) + scsh[C + c];
    v = v >= 0.f ? v : 0.2f * v;
    out[((size_t)b * M + m) * out_stride + out_off + c] = v;
}

// ===== GEMM: BM x 64 tile, float4 staging, merged pool, last-block finalize ==
// Last GEMM block (threadfence+atomic counter) reduces the stats partials into
// scale/shift — replaces the standalone bn_finalize launch. Deterministic:
// reduction order is fixed regardless of which block is last.
template <int BM, bool POOL>
__global__ void gemm_kernel(const float* __restrict__ A, const float* __restrict__ W,
                            float* __restrict__ Cout, int M, int N, int K,
                            float* __restrict__ part /*[M/BM][2][N]*/, int nbn,
                            int* __restrict__ cnt, float* __restrict__ scsh,
                            const float* __restrict__ g, const float* __restrict__ bb, int R,
                            const float* __restrict__ pf, const int* __restrict__ pidx,
                            float* __restrict__ pout, int pNf, int pC, int pstride, int poff) {
    constexpr int RM = BM / 16;
    int t = threadIdx.x;
    int nbm = M / BM;
    int bx = blockIdx.x;
    if (POOL && bx >= nbm * nbn) {
        int e = bx - nbm * nbn;
        int rows = 256 / pC;
        int bpb = 64 / rows;
        int b = e / bpb, mi = e % bpb;
        int m = mi * rows + t / pC;
        int c = t % pC;
        const int* ip = pidx + ((size_t)b * 64 + m) * KNN;
        const float* fb = pf + (size_t)b * pNf * pC;
        float mx = -3.4e38f;
#pragma unroll
        for (int k = 0; k < KNN; ++k) mx = fmaxf(mx, fb[(size_t)ip[k] * pC + c]);
        pout[((size_t)b * 64 + m) * pstride + poff + c] = mx;
        return;
    }
    int bm = bx / nbn, bn = bx % nbn;
    __shared__ float As[16][BM + 4], Ws[16][68];
    __shared__ float2 sred[16][64];
    __shared__ int lastflag;
    int tx = t & 15, ty = t >> 4;
    const float* Ab = A + (size_t)bm * BM * K;
    const float* Wb = W + (size_t)bn * 64 * K;
    float acc[RM][4] = {};
    int srow = t >> 2, skb = (t & 3) << 2;
    for (int k0 = 0; k0 < K; k0 += 16) {
        if (t < BM * 4) {
            float4 av = *(const float4*)&Ab[(size_t)srow * K + k0 + skb];
            As[skb][srow] = av.x; As[skb + 1][srow] = av.y;
            As[skb + 2][srow] = av.z; As[skb + 3][srow] = av.w;
        }
        {
            float4 wv = *(const float4*)&Wb[(size_t)srow * K + k0 + skb];
            Ws[skb][srow] = wv.x; Ws[skb + 1][srow] = wv.y;
            Ws[skb + 2][srow] = wv.z; Ws[skb + 3][srow] = wv.w;
        }
        __syncthreads();
#pragma unroll
        for (int kk = 0; kk < 16; ++kk) {
            float av[RM];
#pragma unroll
            for (int i = 0; i < RM; ++i) av[i] = As[kk][ty * RM + i];
            float4 w4 = *(const float4*)&Ws[kk][tx * 4];
            float wv[4] = {w4.x, w4.y, w4.z, w4.w};
#pragma unroll
            for (int i = 0; i < RM; ++i)
#pragma unroll
                for (int j = 0; j < 4; ++j) acc[i][j] += av[i] * wv[j];
        }
        __syncthreads();
    }
#pragma unroll
    for (int i = 0; i < RM; ++i) {
        float4 v = make_float4(acc[i][0], acc[i][1], acc[i][2], acc[i][3]);
        *(float4*)&Cout[(size_t)(bm * BM + ty * RM + i) * N + bn * 64 + tx * 4] = v;
    }
#pragma unroll
    for (int j = 0; j < 4; ++j) {
        float s = 0.f, q = 0.f;
#pragma unroll
        for (int i = 0; i < RM; ++i) { s += acc[i][j]; q += acc[i][j] * acc[i][j]; }
        sred[ty][tx * 4 + j] = make_float2(s, q);
    }
    __syncthreads();
    if (t < 64) {
        float s = 0.f, q = 0.f;
#pragma unroll
        for (int r = 0; r < 16; ++r) { s += sred[r][t].x; q += sred[r][t].y; }
        part[(size_t)bm * 2 * N + bn * 64 + t] = s;
        part[(size_t)bm * 2 * N + N + bn * 64 + t] = q;
    }
    __syncthreads();
    if (t == 0) {
        __threadfence();
        int old = atomicAdd(cnt, 1);
        lastflag = (old == nbm * nbn - 1);
    }
    __syncthreads();
    if (!lastflag) return;
    __threadfence();
    // ---- last block: reduce partials -> scale/shift
    for (int c0 = 0; c0 < N; c0 += 64) {
        int c = c0 + (t & 63);
        int pc = t >> 6;            // 4 part-chunks
        float s = 0.f, q = 0.f;
        for (int k = pc; k < nbm; k += 4) {
            s += part[(size_t)k * 2 * N + c];
            q += part[(size_t)k * 2 * N + N + c];
        }
        sred[pc][t & 63] = make_float2(s, q);
        __syncthreads();
        if (t < 64) {
            float ss = sred[0][t].x + sred[1][t].x + sred[2][t].x + sred[3][t].x;
            float qq = sred[0][t].y + sred[1][t].y + sred[2][t].y + sred[3][t].y;
            float mean = ss / (float)R;
            float var = qq / (float)R - mean * mean;
            float a = g[c0 + t] * rsqrtf(var + BN_EPS);
            scsh[c0 + t] = a;
            scsh[N + c0 + t] = bb[c0 + t] - mean * a;
        }
        __syncthreads();
    }
}

// ============ global max+mean pool with fused bn+lrelu ============
__global__ void global_pool_bn_kernel(const float* __restrict__ h,
                                      const float* __restrict__ scsh,
                                      float* __restrict__ out) {
    int c = blockIdx.x * 256 + threadIdx.x;   // C=1024
    int b = blockIdx.y;
    const float* hb = h + (size_t)b * 64 * 1024;
    float a = scsh[c], sh = scsh[1024 + c];
    float mx = -3.4e38f, s = 0.f;
    for (int r = 0; r < 64; ++r) {
        float v = a * hb[r * 1024 + c] + sh;
        v = v >= 0.f ? v : 0.2f * v;
        mx = fmaxf(mx, v); s += v;
    }
    out[b * 2048 + c] = mx;
    out[b * 2048 + 1024 + c] = s * (1.f / 64.f);
}

// ==== head1: out[m,n] = A[m,:] . W[n,:]  (K=2048), 4-way K-split + LDS red ===
__global__ void head_gemm_wide(const float* __restrict__ A, const float* __restrict__ W,
                               float* __restrict__ out, int N, int K) {
    __shared__ float red[4][64];
    int t = threadIdx.x;     // 256
    int m = blockIdx.y;
    int nl = t & 63, kq = t >> 6;
    int n = blockIdx.x * 64 + nl;
    int Kc = K >> 2;
    const float4* a4 = (const float4*)(A + (size_t)m * K + kq * Kc);
    const float4* w4 = (const float4*)(W + (size_t)n * K + kq * Kc);
    float s = 0.f;
    for (int k = 0; k < (Kc >> 2); ++k) {
        float4 a = a4[k], w = w4[k];
        s += a.x * w.x + a.y * w.y + a.z * w.z + a.w * w.w;
    }
    red[kq][nl] = s;
    __syncthreads();
    if (t < 64)
        out[(size_t)m * N + blockIdx.x * 64 + t] = red[0][t] + red[1][t] + red[2][t] + red[3][t];
}

// ==== head2 (+ fused head3 in last block) ====
// h7pre[m,n] = (bn_lrelu(h6pre))[m,:].l2w[n,:]+l2b; last block then computes
// outp = (bn_lrelu(h7pre)) @ l3w.T + l3b for all 16 rows.
__global__ void head_bn_gemm2(const float* __restrict__ Apre,
                              const float* __restrict__ g, const float* __restrict__ bb,
                              const float* __restrict__ W, const float* __restrict__ bias,
                              float* __restrict__ out7, int* __restrict__ cnt,
                              const float* __restrict__ g7, const float* __restrict__ bb7,
                              const float* __restrict__ W3, const float* __restrict__ bias3,
                              float* __restrict__ outp) {
    __shared__ float An[512];
    __shared__ float red[4][64];
    __shared__ float An3[16][257];
    __shared__ int lastflag;
    int t = threadIdx.x;     // 256
    int m = blockIdx.y;
    for (int c = t; c < 512; c += 256) {
        float s = 0.f, q = 0.f, vm = 0.f;
#pragma unroll
        for (int r = 0; r < 16; ++r) {
            float v = Apre[r * 512 + c];
            s += v; q += v * v;
            if (r == m) vm = v;
        }
        float mean = s * (1.f / 16.f);
        float var = q * (1.f / 16.f) - mean * mean;
        float a = g[c] * rsqrtf(var + BN_EPS);
        float v = a * (vm - mean) + bb[c];
        An[c] = v >= 0.f ? v : 0.2f * v;
    }
    __syncthreads();
    int nl = t & 63, kq = t >> 6;
    int n = blockIdx.x * 64 + nl;
    const float* wn = W + (size_t)n * 512 + kq * 128;
    const float* an = An + kq * 128;
    float s = 0.f;
    for (int k = 0; k < 128; k += 4) {
        float4 a4 = *(const float4*)&an[k];
        float4 w4 = *(const float4*)&wn[k];
        s += a4.x * w4.x + a4.y * w4.y + a4.z * w4.z + a4.w * w4.w;
    }
    red[kq][nl] = s;
    __syncthreads();
    if (t < 64) {
        float r = red[0][t] + red[1][t] + red[2][t] + red[3][t];
        out7[(size_t)m * 256 + blockIdx.x * 64 + t] = r + bias[blockIdx.x * 64 + t];
    }
    __syncthreads();
    if (t == 0) {
        __threadfence();
        int old = atomicAdd(cnt, 1);
        lastflag = (old == 4 * 16 - 1);
    }
    __syncthreads();
    if (!lastflag) return;
    __threadfence();
    // ---- fused head3 (one block): BN+lrelu columns of h7pre, then 16x40 GEMM
    {
        int c = t;   // 0..255
        float vals[16];
        float ss = 0.f, qq = 0.f;
#pragma unroll
        for (int r = 0; r < 16; ++r) {
            float v = out7[r * 256 + c];
            vals[r] = v; ss += v; qq += v * v;
        }
        float mean = ss * (1.f / 16.f);
        float var = qq * (1.f / 16.f) - mean * mean;
        float a = g7[c] * rsqrtf(var + BN_EPS);
        float sh = bb7[c] - mean * a;
#pragma unroll
        for (int r = 0; r < 16; ++r) {
            float v = a * vals[r] + sh;
            An3[r][c] = v >= 0.f ? v : 0.2f * v;
        }
    }
    __syncthreads();
    for (int o = t; o < 16 * 40; o += 256) {
        int mm = o / 40, nn = o % 40;
        const float* w3 = W3 + (size_t)nn * 256;
        float acc = 0.f;
        for (int k = 0; k < 256; k += 4) {
            acc += An3[mm][k] * w3[k] + An3[mm][k + 1] * w3[k + 1] +
                   An3[mm][k + 2] * w3[k + 2] + An3[mm][k + 3] * w3[k + 3];
        }
        outp[(size_t)mm * 40 + nn] = acc + bias3[nn];
    }
}

extern "C" void kernel_launch(void* const* d_in, const int* in_sizes, int n_in,
                              void* d_out, int out_size, void* d_ws, size_t ws_size,
                              hipStream_t stream) {
    const int B = 16, N = 4096;
    const float* x   = (const float*)d_in[0];
    const float* w1  = (const float*)d_in[1];
    const float* g1  = (const float*)d_in[2];
    const float* b1  = (const float*)d_in[3];
    const float* w2  = (const float*)d_in[4];
    const float* g2  = (const float*)d_in[5];
    const float* b2  = (const float*)d_in[6];
    const float* w3  = (const float*)d_in[7];
    const float* g3  = (const float*)d_in[8];
    const float* b3  = (const float*)d_in[9];
    const float* w4  = (const float*)d_in[10];
    const float* g4  = (const float*)d_in[11];
    const float* b4  = (const float*)d_in[12];
    const float* w5  = (const float*)d_in[13];
    const float* g5  = (const float*)d_in[14];
    const float* b5  = (const float*)d_in[15];
    const float* l1w = (const float*)d_in[16];
    const float* g6  = (const float*)d_in[17];
    const float* b6  = (const float*)d_in[18];
    const float* l2w = (const float*)d_in[19];
    const float* l2b = (const float*)d_in[20];
    const float* g7  = (const float*)d_in[21];
    const float* b7  = (const float*)d_in[22];
    const float* l3w = (const float*)d_in[23];
    const float* l3b = (const float*)d_in[24];
    float* outp = (float*)d_out;

    char* ws = (char*)d_ws;
    size_t off = 0;
    auto alloc = [&](size_t bytes) -> void* {
        void* p = ws + off;
        off += (bytes + 255) & ~(size_t)255;
        return p;
    };
    float* f1p   = (float*)alloc((size_t)B * 1024 * 64 * 4);
    float* f2pre = (float*)alloc((size_t)B * 1024 * 64 * 4);
    float* f2p   = (float*)alloc((size_t)B * 256 * 64 * 4);
    float* f3pre = (float*)alloc((size_t)B * 256 * 128 * 4);
    float* f3p   = (float*)alloc((size_t)B * 128 * 128 * 4);
    float* f4pre = (float*)alloc((size_t)B * 128 * 256 * 4);
    float* hcat  = (float*)alloc((size_t)B * 64 * 512 * 4);
    float* h5pre = (float*)alloc((size_t)B * 64 * 1024 * 4);
    float* hg    = (float*)alloc((size_t)B * 2048 * 4);
    float* h6pre = (float*)alloc((size_t)B * 512 * 4);
    float* h7pre = (float*)alloc((size_t)B * 256 * 4);
    int* idxA = (int*)alloc((size_t)B * 1024 * KNN * 4);
    int* idxB = (int*)alloc((size_t)B * 64 * KNN * 4);
    int* idxC = (int*)alloc((size_t)B * 256 * KNN * 4);
    int* idxD = (int*)alloc((size_t)B * 64 * KNN * 4);
    int* idxE = (int*)alloc((size_t)B * 128 * KNN * 4);
    int* idxF = (int*)alloc((size_t)B * 64 * KNN * 4);
    float* mom   = (float*)alloc((size_t)B * 4 * 9 * 4);
    float4* pkbuf = (float4*)alloc((size_t)B * N * 16);
    float* part2 = (float*)alloc((size_t)512 * 2 * 64 * 4);
    float* part3 = (float*)alloc((size_t)128 * 2 * 128 * 4);
    float* part4 = (float*)alloc((size_t)64 * 2 * 256 * 4);
    float* part5 = (float*)alloc((size_t)32 * 2 * 1024 * 4);
    float* sc2 = (float*)alloc(2 * 64 * 4);
    float* sc3 = (float*)alloc(2 * 128 * 4);
    float* sc4 = (float*)alloc(2 * 256 * 4);
    float* sc5 = (float*)alloc(2 * 1024 * 4);
    int* cnts  = (int*)alloc(8 * 4);

    // reset last-block counters (captured op; re-zeroed every replay)
    hipMemsetAsync(cnts, 0, 8 * 4, stream);

    // ---- moments + packed points, then KNN (all 6 tasks, lean)
    moments3_kernel<<<dim3(B, 4), 256, 0, stream>>>(x, N, mom, pkbuf);
    knn_all_kernel<<<dim3(200, B), 256, 0, stream>>>(pkbuf, N, idxA, idxB, idxC, idxD, idxE, idxF);

    // ---- stage 1 pool
    pool1_kernel<<<dim3(256, B), dim3(64, 4), 0, stream>>>(pkbuf, N, idxA, w1, mom, g1, b1,
                                                           1.f / (B * N), B * 4, f1p, 1024);

    // ---- stage 2: gemm (512) + merged pool B (256) + last-block finalize
    gemm_kernel<32, true><<<dim3(512 + 256), 256, 0, stream>>>(
        f1p, w2, f2pre, B * 1024, 64, 64, part2, 1,
        cnts + 0, sc2, g2, b2, B * 1024,
        f1p, idxB, hcat, 1024, 64, 512, 0);
    pool_bn_kernel<<<dim3(64, B), dim3(64, 4), 0, stream>>>(f2pre, idxC, f2p, 256, 1024, 64, 64, 0, sc2);

    // ---- stage 3: gemm (256) + merged pool D (256) + finalize
    gemm_kernel<32, true><<<dim3(256 + 256), 256, 0, stream>>>(
        f2p, w3, f3pre, B * 256, 128, 64, part3, 2,
        cnts + 1, sc3, g3, b3, B * 256,
        f2p, idxD, hcat, 256, 64, 512, 64);
    pool_bn_kernel<<<dim3(64, B), dim3(128, 2), 0, stream>>>(f3pre, idxE, f3p, 128, 256, 128, 128, 0, sc3);

    // ---- stage 4: gemm (256) + merged pool F (512) + finalize
    gemm_kernel<32, true><<<dim3(256 + 512), 256, 0, stream>>>(
        f3p, w4, f4pre, B * 128, 256, 128, part4, 4,
        cnts + 2, sc4, g4, b4, B * 128,
        f3p, idxF, hcat, 128, 128, 512, 128);
    pool_bn_kernel<<<dim3(64, B), dim3(256, 1), 0, stream>>>(f4pre, idxF, hcat, 64, 128, 256, 512, 256, sc4);

    // ---- stage 5: gemm (512) + finalize
    gemm_kernel<32, false><<<dim3(512), 256, 0, stream>>>(
        hcat, w5, h5pre, B * 64, 1024, 512, part5, 16,
        cnts + 3, sc5, g5, b5, B * 64,
        nullptr, nullptr, nullptr, 0, 1, 0, 0);
    global_pool_bn_kernel<<<dim3(4, B), 256, 0, stream>>>(h5pre, sc5, hg);

    // ---- head (head3 fused into head2's last block)
    head_gemm_wide<<<dim3(8, B), 256, 0, stream>>>(hg, l1w, h6pre, 512, 2048);
    head_bn_gemm2<<<dim3(4, B), 256, 0, stream>>>(h6pre, g6, b6, l2w, l2b, h7pre,
                                                  cnts + 4, g7, b7, l3w, l3b, outp);
}

// Round 14
// 246.754 us; speedup vs baseline: 1.6623x; 1.6623x over previous
//
#include <hip/hip_runtime.h>

#define BN_EPS 1e-5f
#define KNN 20

static inline int ceildiv(int a, int b) { return (a + b - 1) / b; }

// ---- 64-bit xor-shuffle for the one-time bitonic init ----
__device__ __forceinline__ unsigned long long shflxor64(unsigned long long v, int m, int w) {
    int lo = __shfl_xor((int)(unsigned)(v & 0xffffffffull), m, w);
    int hi = __shfl_xor((int)(unsigned)(v >> 32), m, w);
    return ((unsigned long long)(unsigned)hi << 32) | (unsigned)lo;
}

// ====== stage-1 moments (Σp, Σppᵀ per chunk) + packed float4(x,y,z,|p|²) =====
__global__ void moments3_kernel(const float* __restrict__ x, int N,
                                float* __restrict__ part /*[B*4][9]*/,
                                float4* __restrict__ pk /*[B][N]*/) {
    int b = blockIdx.x;
    int chunk = blockIdx.y;          // 4 chunks of N/4
    int t = threadIdx.x;             // 256
    int n0 = chunk * (N >> 2);
    int n1 = n0 + (N >> 2);
    const float* xb = x + (size_t)b * 3 * N;
    float m[9] = {0, 0, 0, 0, 0, 0, 0, 0, 0};
    for (int n = n0 + t; n < n1; n += 256) {
        float px = xb[n], py = xb[N + n], pz = xb[2 * N + n];
        float nr = px * px + py * py + pz * pz;
        pk[(size_t)b * N + n] = make_float4(px, py, pz, nr);
        m[0] += px; m[1] += py; m[2] += pz;
        m[3] += px * px; m[4] += py * py; m[5] += pz * pz;
        m[6] += px * py; m[7] += px * pz; m[8] += py * pz;
    }
#pragma unroll
    for (int o = 32; o; o >>= 1)
#pragma unroll
        for (int i = 0; i < 9; ++i) m[i] += __shfl_down(m[i], o);
    __shared__ float red[4][9];
    if ((t & 63) == 0)
#pragma unroll
        for (int i = 0; i < 9; ++i) red[t >> 6][i] = m[i];
    __syncthreads();
    if (t == 0) {
#pragma unroll
        for (int i = 0; i < 9; ++i)
            part[(b * 4 + chunk) * 9 + i] = red[0][i] + red[1][i] + red[2][i] + red[3][i];
    }
}

// ============ KNN: 2 queries/wave, f32 scan keys, u64 bitonic init ==========
// Lean version (VGPR ~16): no fused epilogue — occupancy carries the scan.
__global__ void knn_all_kernel(const float4* __restrict__ pk, int Nstride,
                               int* __restrict__ iA, int* __restrict__ iB,
                               int* __restrict__ iC, int* __restrict__ iD,
                               int* __restrict__ iE, int* __restrict__ iF) {
    int b = blockIdx.y;
    int bx = blockIdx.x;
    int M, N; int* out; int qbase;
    if (bx < 128)      { M = 1024; N = 4096; out = iA; qbase = bx * 8; }
    else if (bx < 136) { M = 64;   N = 1024; out = iB; qbase = (bx - 128) * 8; }
    else if (bx < 168) { M = 256;  N = 1024; out = iC; qbase = (bx - 136) * 8; }
    else if (bx < 176) { M = 64;   N = 256;  out = iD; qbase = (bx - 168) * 8; }
    else if (bx < 192) { M = 128;  N = 256;  out = iE; qbase = (bx - 176) * 8; }
    else               { M = 64;   N = 128;  out = iF; qbase = (bx - 192) * 8; }
    int wave = threadIdx.x >> 6;
    int lane = threadIdx.x & 63;
    int sl = lane & 31;          // segment lane
    int half = lane >> 5;        // which query of the pair
    int q = qbase + wave * 2 + half;
    const float4* pb = pk + (size_t)b * Nstride;
    float4 qp = pb[q];

    auto dist = [&](int j) -> float {
        float4 c = pb[j];
        return qp.w + c.w - 2.f * (qp.x * c.x + qp.y * c.y + qp.z * c.z);
    };

    int up_addr = ((sl == 0) ? lane : (lane - 1)) << 2;
    int wd_addr = (19 + (half << 5)) << 2;
    int segbyte = half << 7;

    unsigned long long lk;
    {
        float d2 = dist(sl);
        unsigned u = __float_as_uint(d2);
        unsigned ok = (u & 0x80000000u) ? ~u : (u | 0x80000000u);
        lk = ((unsigned long long)ok << 32) | (unsigned)sl;
    }
#pragma unroll
    for (int size = 2; size <= 32; size <<= 1) {
#pragma unroll
        for (int stride = size >> 1; stride >= 1; stride >>= 1) {
            unsigned long long p = shflxor64(lk, stride, 32);
            bool ascend = (sl & size) == 0;
            bool low = (sl & stride) == 0;
            bool keepMin = (ascend == low);
            bool pLess = p < lk;
            lk = (keepMin == pLess) ? p : lk;
        }
    }
    unsigned okey = (unsigned)(lk >> 32);
    unsigned du = (okey & 0x80000000u) ? (okey ^ 0x80000000u) : ~okey;
    float ld = __uint_as_float(du);
    int li = (int)(unsigned)(lk & 0xffffffffull);
    float wd = __uint_as_float(__builtin_amdgcn_ds_bpermute(wd_addr, (int)__float_as_uint(ld)));

    auto insert2 = [&](float dc, int jb, unsigned long long msk) {
        unsigned mlo = (unsigned)msk, mhi = (unsigned)(msk >> 32);
        while (mlo | mhi) {
            int slo = __ffs((int)mlo) - 1;
            int shi = __ffs((int)mhi) - 1;
            int srcl = half ? shi : slo;
            int addr = ((srcl & 31) << 2) + segbyte;
            float d = __uint_as_float(__builtin_amdgcn_ds_bpermute(addr, (int)__float_as_uint(dc)));
            if (srcl < 0) d = 3.4e38f;
            int id = jb + (srcl & 31);
            float up_d = __uint_as_float(__builtin_amdgcn_ds_bpermute(up_addr, (int)__float_as_uint(ld)));
            int up_i = __builtin_amdgcn_ds_bpermute(up_addr, li);
            bool c = d < ld;
            bool cp = (sl != 0) && (d < up_d);
            ld = c ? (cp ? up_d : d) : ld;
            li = c ? (cp ? up_i : id) : li;
            mlo &= mlo - 1;
            mhi &= mhi - 1;
        }
    };

    {
        float dc = dist(32 + sl);
        unsigned long long m = __ballot(dc < wd);
        if (m) {
            insert2(dc, 32, m);
            wd = __uint_as_float(__builtin_amdgcn_ds_bpermute(wd_addr, (int)__float_as_uint(ld)));
        }
    }
    for (int j0 = 64; j0 < N; j0 += 64) {
        float dc0 = dist(j0 + sl);
        float dc1 = dist(j0 + 32 + sl);
        unsigned long long m0 = __ballot(dc0 < wd);
        unsigned long long m1 = __ballot(dc1 < wd);
        if (m0 | m1) {
            if (m0) insert2(dc0, j0, m0);
            if (m1) insert2(dc1, j0 + 32, m1);
            wd = __uint_as_float(__builtin_amdgcn_ds_bpermute(wd_addr, (int)__float_as_uint(ld)));
        }
    }
    if (sl < KNN) out[((size_t)b * M + q) * KNN + sl] = li;
}

// ============ stage-1 pool: fused finalize1 + gather + dot + bn + lrelu ======
__global__ void pool1_kernel(const float4* __restrict__ pk, int N, const int* __restrict__ idxA,
                             const float* __restrict__ w1, const float* __restrict__ mom,
                             const float* __restrict__ g, const float* __restrict__ bb,
                             float Rinv, int nparts, float* __restrict__ out, int M) {
    __shared__ float S[9];
    __shared__ float sca[64], shb[64];
    int c = threadIdx.x;                    // 64
    int tid = threadIdx.y * 64 + c;
    if (tid < 9) {
        float s = 0.f;
        for (int bi = 0; bi < nparts; ++bi) s += mom[bi * 9 + tid];
        S[tid] = s;
    }
    __syncthreads();
    if (tid < 64) {
        float wx = w1[tid * 3], wy = w1[tid * 3 + 1], wz = w1[tid * 3 + 2];
        float mean = (wx * S[0] + wy * S[1] + wz * S[2]) * Rinv;
        float e2 = (wx * wx * S[3] + wy * wy * S[4] + wz * wz * S[5] +
                    2.f * (wx * wy * S[6] + wx * wz * S[7] + wy * wz * S[8])) * Rinv;
        float var = e2 - mean * mean;
        float a = g[tid] * rsqrtf(var + BN_EPS);
        sca[tid] = a;
        shb[tid] = bb[tid] - mean * a;
    }
    __syncthreads();
    int m = blockIdx.x * 4 + threadIdx.y;
    int b = blockIdx.y;
    const float4* pb = pk + (size_t)b * N;
    const int* ip = idxA + ((size_t)b * M + m) * KNN;
    float wx = w1[c * 3], wy = w1[c * 3 + 1], wz = w1[c * 3 + 2];
    float mx = -3.4e38f, mn = 3.4e38f;
#pragma unroll
    for (int k = 0; k < KNN; ++k) {
        float4 p = pb[ip[k]];
        float d = wx * p.x + wy * p.y + wz * p.z;
        mx = fmaxf(mx, d); mn = fminf(mn, d);
    }
    float a = sca[c];
    float v = a * (a >= 0.f ? mx : mn) + shb[c];
    out[((size_t)b * M + m) * 64 + c] = v >= 0.f ? v : 0.2f * v;
}

// ====== gather pool with bn+lrelu from scsh (min/max trick) ============
__global__ void pool_bn_kernel(const float* __restrict__ f, const int* __restrict__ idx,
                               float* __restrict__ out, int M, int Nf, int C,
                               int out_stride, int out_off, const float* __restrict__ scsh) {
    int c = threadIdx.x;                               // blockDim.x == C
    int m = blockIdx.x * blockDim.y + threadIdx.y;
    int b = blockIdx.y;
    const int* ip = idx + ((size_t)b * M + m) * KNN;
    const float* fb = f + (size_t)b * Nf * C;
    float mx = -3.4e38f, mn = 3.4e38f;
#pragma unroll
    for (int k = 0; k < KNN; ++k) {
        int j = ip[k];
        float v = fb[(size_t)j * C + c];
        mx = fmaxf(mx, v);
        mn = fminf(mn, v);
    }
    float a = scsh[c];
    float v = a * (a >= 0.f ? mx : mn) + scsh[C + c];
    v = v >= 0.f ? v : 0.2f * v;
    out[((size_t)b * M + m) * out_stride + out_off + c] = v;
}

// ===== GEMM: BM x 64 tile, float4 staging, BN-stats epilogue, merged pool ====
template <int BM, bool POOL>
__global__ void gemm_kernel(const float* __restrict__ A, const float* __restrict__ W,
                            float* __restrict__ Cout, int M, int N, int K,
                            float* __restrict__ part /*[M/BM][2][N]*/, int nbn,
                            const float* __restrict__ pf, const int* __restrict__ pidx,
                            float* __restrict__ pout, int pNf, int pC, int pstride, int poff) {
    constexpr int RM = BM / 16;
    int t = threadIdx.x;
    int nbm = M / BM;
    int bx = blockIdx.x;
    if (POOL && bx >= nbm * nbn) {
        int e = bx - nbm * nbn;
        int rows = 256 / pC;
        int bpb = 64 / rows;
        int b = e / bpb, mi = e % bpb;
        int m = mi * rows + t / pC;
        int c = t % pC;
        const int* ip = pidx + ((size_t)b * 64 + m) * KNN;
        const float* fb = pf + (size_t)b * pNf * pC;
        float mx = -3.4e38f;
#pragma unroll
        for (int k = 0; k < KNN; ++k) mx = fmaxf(mx, fb[(size_t)ip[k] * pC + c]);
        pout[((size_t)b * 64 + m) * pstride + poff + c] = mx;
        return;
    }
    int bm = bx / nbn, bn = bx % nbn;
    __shared__ float As[16][BM + 4], Ws[16][68];
    int tx = t & 15, ty = t >> 4;
    const float* Ab = A + (size_t)bm * BM * K;
    const float* Wb = W + (size_t)bn * 64 * K;
    float acc[RM][4] = {};
    int srow = t >> 2, skb = (t & 3) << 2;
    for (int k0 = 0; k0 < K; k0 += 16) {
        if (t < BM * 4) {
            float4 av = *(const float4*)&Ab[(size_t)srow * K + k0 + skb];
            As[skb][srow] = av.x; As[skb + 1][srow] = av.y;
            As[skb + 2][srow] = av.z; As[skb + 3][srow] = av.w;
        }
        {
            float4 wv = *(const float4*)&Wb[(size_t)srow * K + k0 + skb];
            Ws[skb][srow] = wv.x; Ws[skb + 1][srow] = wv.y;
            Ws[skb + 2][srow] = wv.z; Ws[skb + 3][srow] = wv.w;
        }
        __syncthreads();
#pragma unroll
        for (int kk = 0; kk < 16; ++kk) {
            float av[RM];
#pragma unroll
            for (int i = 0; i < RM; ++i) av[i] = As[kk][ty * RM + i];
            float4 w4 = *(const float4*)&Ws[kk][tx * 4];
            float wv[4] = {w4.x, w4.y, w4.z, w4.w};
#pragma unroll
            for (int i = 0; i < RM; ++i)
#pragma unroll
                for (int j = 0; j < 4; ++j) acc[i][j] += av[i] * wv[j];
        }
        __syncthreads();
    }
#pragma unroll
    for (int i = 0; i < RM; ++i) {
        float4 v = make_float4(acc[i][0], acc[i][1], acc[i][2], acc[i][3]);
        *(float4*)&Cout[(size_t)(bm * BM + ty * RM + i) * N + bn * 64 + tx * 4] = v;
    }
    __shared__ float2 sred[16][64];
#pragma unroll
    for (int j = 0; j < 4; ++j) {
        float s = 0.f, q = 0.f;
#pragma unroll
        for (int i = 0; i < RM; ++i) { s += acc[i][j]; q += acc[i][j] * acc[i][j]; }
        sred[ty][tx * 4 + j] = make_float2(s, q);
    }
    __syncthreads();
    if (t < 64) {
        float s = 0.f, q = 0.f;
#pragma unroll
        for (int r = 0; r < 16; ++r) { s += sred[r][t].x; q += sred[r][t].y; }
        part[(size_t)bm * 2 * N + bn * 64 + t] = s;
        part[(size_t)bm * 2 * N + N + bn * 64 + t] = q;
    }
}

// partials -> scale/shift
__global__ void bn_finalize_kernel(const float* __restrict__ part, int nparts, int C, int R,
                                   const float* __restrict__ g, const float* __restrict__ bb,
                                   float* __restrict__ scsh) {
    int c = blockIdx.x;
    int t = threadIdx.x;   // 256
    float s = 0.f, q = 0.f;
    for (int k = t; k < nparts; k += 256) {
        s += part[(size_t)k * 2 * C + c];
        q += part[(size_t)k * 2 * C + C + c];
    }
#pragma unroll
    for (int o = 32; o; o >>= 1) { s += __shfl_down(s, o); q += __shfl_down(q, o); }
    __shared__ float2 red[4];
    if ((t & 63) == 0) red[t >> 6] = make_float2(s, q);
    __syncthreads();
    if (t == 0) {
        s = red[0].x + red[1].x + red[2].x + red[3].x;
        q = red[0].y + red[1].y + red[2].y + red[3].y;
        float mean = s / (float)R;
        float var = q / (float)R - mean * mean;
        float a = g[c] * rsqrtf(var + BN_EPS);
        scsh[c] = a;
        scsh[C + c] = bb[c] - mean * a;
    }
}

// ============ global max+mean pool with fused bn+lrelu ============
__global__ void global_pool_bn_kernel(const float* __restrict__ h,
                                      const float* __restrict__ scsh,
                                      float* __restrict__ out) {
    int c = blockIdx.x * 256 + threadIdx.x;   // C=1024
    int b = blockIdx.y;
    const float* hb = h + (size_t)b * 64 * 1024;
    float a = scsh[c], sh = scsh[1024 + c];
    float mx = -3.4e38f, s = 0.f;
    for (int r = 0; r < 64; ++r) {
        float v = a * hb[r * 1024 + c] + sh;
        v = v >= 0.f ? v : 0.2f * v;
        mx = fmaxf(mx, v); s += v;
    }
    out[b * 2048 + c] = mx;
    out[b * 2048 + 1024 + c] = s * (1.f / 64.f);
}

// ==== head1: out[m,n] = A[m,:] . W[n,:]  (K=2048), 4-way K-split + LDS red ===
__global__ void head_gemm_wide(const float* __restrict__ A, const float* __restrict__ W,
                               float* __restrict__ out, int N, int K) {
    __shared__ float red[4][64];
    int t = threadIdx.x;     // 256
    int m = blockIdx.y;
    int nl = t & 63, kq = t >> 6;
    int n = blockIdx.x * 64 + nl;
    int Kc = K >> 2;
    const float4* a4 = (const float4*)(A + (size_t)m * K + kq * Kc);
    const float4* w4 = (const float4*)(W + (size_t)n * K + kq * Kc);
    float s = 0.f;
    for (int k = 0; k < (Kc >> 2); ++k) {
        float4 a = a4[k], w = w4[k];
        s += a.x * w.x + a.y * w.y + a.z * w.z + a.w * w.w;
    }
    red[kq][nl] = s;
    __syncthreads();
    if (t < 64)
        out[(size_t)m * N + blockIdx.x * 64 + t] = red[0][t] + red[1][t] + red[2][t] + red[3][t];
}

// ==== head2: h7pre[m,n] = (bn_lrelu(h6pre))[m,:] . l2w[n,:] + l2b  (K=512) ====
__global__ void head_bn_gemm2(const float* __restrict__ Apre,
                              const float* __restrict__ g, const float* __restrict__ bb,
                              const float* __restrict__ W, const float* __restrict__ bias,
                              float* __restrict__ out) {
    __shared__ float An[512];
    __shared__ float red[4][64];
    int t = threadIdx.x;     // 256
    int m = blockIdx.y;
    for (int c = t; c < 512; c += 256) {
        float s = 0.f, q = 0.f, vm = 0.f;
#pragma unroll
        for (int r = 0; r < 16; ++r) {
            float v = Apre[r * 512 + c];
            s += v; q += v * v;
            if (r == m) vm = v;
        }
        float mean = s * (1.f / 16.f);
        float var = q * (1.f / 16.f) - mean * mean;
        float a = g[c] * rsqrtf(var + BN_EPS);
        float v = a * (vm - mean) + bb[c];
        An[c] = v >= 0.f ? v : 0.2f * v;
    }
    __syncthreads();
    int nl = t & 63, kq = t >> 6;
    int n = blockIdx.x * 64 + nl;
    const float* wn = W + (size_t)n * 512 + kq * 128;
    const float* an = An + kq * 128;
    float s = 0.f;
    for (int k = 0; k < 128; k += 4) {
        float4 a4 = *(const float4*)&an[k];
        float4 w4 = *(const float4*)&wn[k];
        s += a4.x * w4.x + a4.y * w4.y + a4.z * w4.z + a4.w * w4.w;
    }
    red[kq][nl] = s;
    __syncthreads();
    if (t < 64) {
        float r = red[0][t] + red[1][t] + red[2][t] + red[3][t];
        out[(size_t)m * 256 + blockIdx.x * 64 + t] = r + bias[blockIdx.x * 64 + t];
    }
}

// ==== head3: out[m,n] = (bn_lrelu(h7pre))[m,:] . l3w[n,:] + l3b (K=256,N=40) ==
__global__ void head_bn_gemm3(const float* __restrict__ Apre,
                              const float* __restrict__ g, const float* __restrict__ bb,
                              const float* __restrict__ W, const float* __restrict__ bias,
                              float* __restrict__ out) {
    __shared__ float An[256];
    __shared__ float red[4][64];
    int t = threadIdx.x;     // 256
    int m = blockIdx.x;
    {
        int c = t;
        float s = 0.f, q = 0.f, vm = 0.f;
#pragma unroll
        for (int r = 0; r < 16; ++r) {
            float v = Apre[r * 256 + c];
            s += v; q += v * v;
            if (r == m) vm = v;
        }
        float mean = s * (1.f / 16.f);
        float var = q * (1.f / 16.f) - mean * mean;
        float a = g[c] * rsqrtf(var + BN_EPS);
        float v = a * (vm - mean) + bb[c];
        An[c] = v >= 0.f ? v : 0.2f * v;
    }
    __syncthreads();
    int nl = t & 63, kq = t >> 6;
    float s = 0.f;
    if (nl < 40) {
        const float* wn = W + (size_t)nl * 256 + kq * 64;
        const float* an = An + kq * 64;
        for (int k = 0; k < 64; k += 4) {
            float4 a4 = *(const float4*)&an[k];
            float4 w4 = *(const float4*)&wn[k];
            s += a4.x * w4.x + a4.y * w4.y + a4.z * w4.z + a4.w * w4.w;
        }
    }
    red[kq][nl] = s;
    __syncthreads();
    if (t < 40) {
        float r = red[0][t] + red[1][t] + red[2][t] + red[3][t];
        out[(size_t)m * 40 + t] = r + bias[t];
    }
}

extern "C" void kernel_launch(void* const* d_in, const int* in_sizes, int n_in,
                              void* d_out, int out_size, void* d_ws, size_t ws_size,
                              hipStream_t stream) {
    const int B = 16, N = 4096;
    const float* x   = (const float*)d_in[0];
    const float* w1  = (const float*)d_in[1];
    const float* g1  = (const float*)d_in[2];
    const float* b1  = (const float*)d_in[3];
    const float* w2  = (const float*)d_in[4];
    const float* g2  = (const float*)d_in[5];
    const float* b2  = (const float*)d_in[6];
    const float* w3  = (const float*)d_in[7];
    const float* g3  = (const float*)d_in[8];
    const float* b3  = (const float*)d_in[9];
    const float* w4  = (const float*)d_in[10];
    const float* g4  = (const float*)d_in[11];
    const float* b4  = (const float*)d_in[12];
    const float* w5  = (const float*)d_in[13];
    const float* g5  = (const float*)d_in[14];
    const float* b5  = (const float*)d_in[15];
    const float* l1w = (const float*)d_in[16];
    const float* g6  = (const float*)d_in[17];
    const float* b6  = (const float*)d_in[18];
    const float* l2w = (const float*)d_in[19];
    const float* l2b = (const float*)d_in[20];
    const float* g7  = (const float*)d_in[21];
    const float* b7  = (const float*)d_in[22];
    const float* l3w = (const float*)d_in[23];
    const float* l3b = (const float*)d_in[24];
    float* outp = (float*)d_out;

    char* ws = (char*)d_ws;
    size_t off = 0;
    auto alloc = [&](size_t bytes) -> void* {
        void* p = ws + off;
        off += (bytes + 255) & ~(size_t)255;
        return p;
    };
    float* f1p   = (float*)alloc((size_t)B * 1024 * 64 * 4);
    float* f2pre = (float*)alloc((size_t)B * 1024 * 64 * 4);
    float* f2p   = (float*)alloc((size_t)B * 256 * 64 * 4);
    float* f3pre = (float*)alloc((size_t)B * 256 * 128 * 4);
    float* f3p   = (float*)alloc((size_t)B * 128 * 128 * 4);
    float* f4pre = (float*)alloc((size_t)B * 128 * 256 * 4);
    float* hcat  = (float*)alloc((size_t)B * 64 * 512 * 4);
    float* h5pre = (float*)alloc((size_t)B * 64 * 1024 * 4);
    float* hg    = (float*)alloc((size_t)B * 2048 * 4);
    float* h6pre = (float*)alloc((size_t)B * 512 * 4);
    float* h7pre = (float*)alloc((size_t)B * 256 * 4);
    int* idxA = (int*)alloc((size_t)B * 1024 * KNN * 4);
    int* idxB = (int*)alloc((size_t)B * 64 * KNN * 4);
    int* idxC = (int*)alloc((size_t)B * 256 * KNN * 4);
    int* idxD = (int*)alloc((size_t)B * 64 * KNN * 4);
    int* idxE = (int*)alloc((size_t)B * 128 * KNN * 4);
    int* idxF = (int*)alloc((size_t)B * 64 * KNN * 4);
    float* mom   = (float*)alloc((size_t)B * 4 * 9 * 4);
    float4* pkbuf = (float4*)alloc((size_t)B * N * 16);
    float* part2 = (float*)alloc((size_t)512 * 2 * 64 * 4);
    float* part3 = (float*)alloc((size_t)128 * 2 * 128 * 4);
    float* part4 = (float*)alloc((size_t)64 * 2 * 256 * 4);
    float* part5 = (float*)alloc((size_t)32 * 2 * 1024 * 4);
    float* sc2 = (float*)alloc(2 * 64 * 4);
    float* sc3 = (float*)alloc(2 * 128 * 4);
    float* sc4 = (float*)alloc(2 * 256 * 4);
    float* sc5 = (float*)alloc(2 * 1024 * 4);

    // ---- moments + packed points, then KNN (all 6 tasks, lean)
    moments3_kernel<<<dim3(B, 4), 256, 0, stream>>>(x, N, mom, pkbuf);
    knn_all_kernel<<<dim3(200, B), 256, 0, stream>>>(pkbuf, N, idxA, idxB, idxC, idxD, idxE, idxF);

    // ---- stage 1 pool (standalone; cheap, keeps knn lean)
    pool1_kernel<<<dim3(256, B), dim3(64, 4), 0, stream>>>(pkbuf, N, idxA, w1, mom, g1, b1,
                                                           1.f / (B * N), B * 4, f1p, 1024);

    // ---- stage 2: gemm (512 blocks) + merged pool B (256 blocks)
    gemm_kernel<32, true><<<dim3(512 + 256), 256, 0, stream>>>(
        f1p, w2, f2pre, B * 1024, 64, 64, part2, 1,
        f1p, idxB, hcat, 1024, 64, 512, 0);
    bn_finalize_kernel<<<dim3(64), 256, 0, stream>>>(part2, 512, 64, B * 1024, g2, b2, sc2);
    pool_bn_kernel<<<dim3(64, B), dim3(64, 4), 0, stream>>>(f2pre, idxC, f2p, 256, 1024, 64, 64, 0, sc2);

    // ---- stage 3: gemm (256 blocks) + merged pool D (256 blocks)
    gemm_kernel<32, true><<<dim3(256 + 256), 256, 0, stream>>>(
        f2p, w3, f3pre, B * 256, 128, 64, part3, 2,
        f2p, idxD, hcat, 256, 64, 512, 64);
    bn_finalize_kernel<<<dim3(128), 256, 0, stream>>>(part3, 128, 128, B * 256, g3, b3, sc3);
    pool_bn_kernel<<<dim3(64, B), dim3(128, 2), 0, stream>>>(f3pre, idxE, f3p, 128, 256, 128, 128, 0, sc3);

    // ---- stage 4: gemm (256 blocks) + merged pool F (512 blocks)
    gemm_kernel<32, true><<<dim3(256 + 512), 256, 0, stream>>>(
        f3p, w4, f4pre, B * 128, 256, 128, part4, 4,
        f3p, idxF, hcat, 128, 128, 512, 128);
    bn_finalize_kernel<<<dim3(256), 256, 0, stream>>>(part4, 64, 256, B * 128, g4, b4, sc4);
    pool_bn_kernel<<<dim3(64, B), dim3(256, 1), 0, stream>>>(f4pre, idxF, hcat, 64, 128, 256, 512, 256, sc4);

    // ---- stage 5
    gemm_kernel<32, false><<<dim3(512), 256, 0, stream>>>(
        hcat, w5, h5pre, B * 64, 1024, 512, part5, 16,
        nullptr, nullptr, nullptr, 0, 1, 0, 0);
    bn_finalize_kernel<<<dim3(1024), 256, 0, stream>>>(part5, 32, 1024, B * 64, g5, b5, sc5);
    global_pool_bn_kernel<<<dim3(4, B), 256, 0, stream>>>(h5pre, sc5, hg);

    // ---- head
    head_gemm_wide<<<dim3(8, B), 256, 0, stream>>>(hg, l1w, h6pre, 512, 2048);
    head_bn_gemm2<<<dim3(4, B), 256, 0, stream>>>(h6pre, g6, b6, l2w, l2b, h7pre);
    head_bn_gemm3<<<dim3(B), 256, 0, stream>>>(h7pre, g7, b7, l3w, l3b, outp);
}

// Round 15
// 240.338 us; speedup vs baseline: 1.7066x; 1.0267x over previous
//
#include <hip/hip_runtime.h>

#define BN_EPS 1e-5f
#define KNN 20

static inline int ceildiv(int a, int b) { return (a + b - 1) / b; }

// ---- 64-bit xor-shuffle for the one-time bitonic init ----
__device__ __forceinline__ unsigned long long shflxor64(unsigned long long v, int m, int w) {
    int lo = __shfl_xor((int)(unsigned)(v & 0xffffffffull), m, w);
    int hi = __shfl_xor((int)(unsigned)(v >> 32), m, w);
    return ((unsigned long long)(unsigned)hi << 32) | (unsigned)lo;
}

// ====== stage-1 moments (Σp, Σppᵀ per chunk) + packed float4(x,y,z,½|p|²) ====
__global__ void moments3_kernel(const float* __restrict__ x, int N,
                                float* __restrict__ part /*[B*4][9]*/,
                                float4* __restrict__ pk /*[B][N]*/) {
    int b = blockIdx.x;
    int chunk = blockIdx.y;          // 4 chunks of N/4
    int t = threadIdx.x;             // 256
    int n0 = chunk * (N >> 2);
    int n1 = n0 + (N >> 2);
    const float* xb = x + (size_t)b * 3 * N;
    float m[9] = {0, 0, 0, 0, 0, 0, 0, 0, 0};
    for (int n = n0 + t; n < n1; n += 256) {
        float px = xb[n], py = xb[N + n], pz = xb[2 * N + n];
        float nr = px * px + py * py + pz * pz;
        pk[(size_t)b * N + n] = make_float4(px, py, pz, 0.5f * nr);
        m[0] += px; m[1] += py; m[2] += pz;
        m[3] += px * px; m[4] += py * py; m[5] += pz * pz;
        m[6] += px * py; m[7] += px * pz; m[8] += py * pz;
    }
#pragma unroll
    for (int o = 32; o; o >>= 1)
#pragma unroll
        for (int i = 0; i < 9; ++i) m[i] += __shfl_down(m[i], o);
    __shared__ float red[4][9];
    if ((t & 63) == 0)
#pragma unroll
        for (int i = 0; i < 9; ++i) red[t >> 6][i] = m[i];
    __syncthreads();
    if (t == 0) {
#pragma unroll
        for (int i = 0; i < 9; ++i)
            part[(b * 4 + chunk) * 9 + i] = red[0][i] + red[1][i] + red[2][i] + red[3][i];
    }
}

// ============ KNN: 2 queries/wave, monotone f32 keys, u64 bitonic init ======
// Ranking key: key_j = ½|c_j|² − q·c_j  (d2 = 2·key + |q|², affine, order-
// preserving). Lane sl of each 32-lane segment holds the sl-th best (key,idx).
__global__ void knn_all_kernel(const float4* __restrict__ pk, int Nstride,
                               int* __restrict__ iA, int* __restrict__ iB,
                               int* __restrict__ iC, int* __restrict__ iD,
                               int* __restrict__ iE, int* __restrict__ iF) {
    int b = blockIdx.y;
    int bx = blockIdx.x;
    int M, N; int* out; int qbase;
    if (bx < 128)      { M = 1024; N = 4096; out = iA; qbase = bx * 8; }
    else if (bx < 136) { M = 64;   N = 1024; out = iB; qbase = (bx - 128) * 8; }
    else if (bx < 168) { M = 256;  N = 1024; out = iC; qbase = (bx - 136) * 8; }
    else if (bx < 176) { M = 64;   N = 256;  out = iD; qbase = (bx - 168) * 8; }
    else if (bx < 192) { M = 128;  N = 256;  out = iE; qbase = (bx - 176) * 8; }
    else               { M = 64;   N = 128;  out = iF; qbase = (bx - 192) * 8; }
    int wave = threadIdx.x >> 6;
    int lane = threadIdx.x & 63;
    int sl = lane & 31;          // segment lane
    int half = lane >> 5;        // which query of the pair
    int q = qbase + wave * 2 + half;
    const float4* pb = pk + (size_t)b * Nstride;
    float4 qp = pb[q];

    auto key = [&](int j) -> float {
        float4 c = pb[j];
        return c.w - (qp.x * c.x + qp.y * c.y + qp.z * c.z);
    };

    int up_addr = ((sl == 0) ? lane : (lane - 1)) << 2;
    int wd_addr = (19 + (half << 5)) << 2;
    int segbyte = half << 7;

    unsigned long long lk;
    {
        float d2 = key(sl);
        unsigned u = __float_as_uint(d2);
        unsigned ok = (u & 0x80000000u) ? ~u : (u | 0x80000000u);
        lk = ((unsigned long long)ok << 32) | (unsigned)sl;
    }
#pragma unroll
    for (int size = 2; size <= 32; size <<= 1) {
#pragma unroll
        for (int stride = size >> 1; stride >= 1; stride >>= 1) {
            unsigned long long p = shflxor64(lk, stride, 32);
            bool ascend = (sl & size) == 0;
            bool low = (sl & stride) == 0;
            bool keepMin = (ascend == low);
            bool pLess = p < lk;
            lk = (keepMin == pLess) ? p : lk;
        }
    }
    unsigned okey = (unsigned)(lk >> 32);
    unsigned du = (okey & 0x80000000u) ? (okey ^ 0x80000000u) : ~okey;
    float ld = __uint_as_float(du);
    int li = (int)(unsigned)(lk & 0xffffffffull);
    float wd = __uint_as_float(__builtin_amdgcn_ds_bpermute(wd_addr, (int)__float_as_uint(ld)));

    auto insert2 = [&](float dc, int jb, unsigned long long msk) {
        unsigned mlo = (unsigned)msk, mhi = (unsigned)(msk >> 32);
        while (mlo | mhi) {
            int slo = __ffs((int)mlo) - 1;
            int shi = __ffs((int)mhi) - 1;
            int srcl = half ? shi : slo;
            int addr = ((srcl & 31) << 2) + segbyte;
            float d = __uint_as_float(__builtin_amdgcn_ds_bpermute(addr, (int)__float_as_uint(dc)));
            if (srcl < 0) d = 3.4e38f;
            int id = jb + (srcl & 31);
            float up_d = __uint_as_float(__builtin_amdgcn_ds_bpermute(up_addr, (int)__float_as_uint(ld)));
            int up_i = __builtin_amdgcn_ds_bpermute(up_addr, li);
            bool c = d < ld;
            bool cp = (sl != 0) && (d < up_d);
            ld = c ? (cp ? up_d : d) : ld;
            li = c ? (cp ? up_i : id) : li;
            mlo &= mlo - 1;
            mhi &= mhi - 1;
        }
    };

    {
        float dc = key(32 + sl);
        unsigned long long m = __ballot(dc < wd);
        if (m) {
            insert2(dc, 32, m);
            wd = __uint_as_float(__builtin_amdgcn_ds_bpermute(wd_addr, (int)__float_as_uint(ld)));
        }
    }
    for (int j0 = 64; j0 < N; j0 += 64) {
        float dc0 = key(j0 + sl);
        float dc1 = key(j0 + 32 + sl);
        unsigned long long m0 = __ballot(dc0 < wd);
        unsigned long long m1 = __ballot(dc1 < wd);
        if (m0 | m1) {
            if (m0) insert2(dc0, j0, m0);
            if (m1) insert2(dc1, j0 + 32, m1);
            wd = __uint_as_float(__builtin_amdgcn_ds_bpermute(wd_addr, (int)__float_as_uint(ld)));
        }
    }
    if (sl < KNN) out[((size_t)b * M + q) * KNN + sl] = li;
}

// ============ stage-1 pool: fused finalize1 + gather + dot + bn + lrelu ======
__global__ void pool1_kernel(const float4* __restrict__ pk, int N, const int* __restrict__ idxA,
                             const float* __restrict__ w1, const float* __restrict__ mom,
                             const float* __restrict__ g, const float* __restrict__ bb,
                             float Rinv, int nparts, float* __restrict__ out, int M) {
    __shared__ float S[9];
    __shared__ float sca[64], shb[64];
    int c = threadIdx.x;                    // 64
    int tid = threadIdx.y * 64 + c;
    if (tid < 9) {
        float s = 0.f;
        for (int bi = 0; bi < nparts; ++bi) s += mom[bi * 9 + tid];
        S[tid] = s;
    }
    __syncthreads();
    if (tid < 64) {
        float wx = w1[tid * 3], wy = w1[tid * 3 + 1], wz = w1[tid * 3 + 2];
        float mean = (wx * S[0] + wy * S[1] + wz * S[2]) * Rinv;
        float e2 = (wx * wx * S[3] + wy * wy * S[4] + wz * wz * S[5] +
                    2.f * (wx * wy * S[6] + wx * wz * S[7] + wy * wz * S[8])) * Rinv;
        float var = e2 - mean * mean;
        float a = g[tid] * rsqrtf(var + BN_EPS);
        sca[tid] = a;
        shb[tid] = bb[tid] - mean * a;
    }
    __syncthreads();
    int m = blockIdx.x * 4 + threadIdx.y;
    int b = blockIdx.y;
    const float4* pb = pk + (size_t)b * N;
    const int* ip = idxA + ((size_t)b * M + m) * KNN;
    float wx = w1[c * 3], wy = w1[c * 3 + 1], wz = w1[c * 3 + 2];
    float mx = -3.4e38f, mn = 3.4e38f;
#pragma unroll
    for (int k = 0; k < KNN; ++k) {
        float4 p = pb[ip[k]];
        float d = wx * p.x + wy * p.y + wz * p.z;
        mx = fmaxf(mx, d); mn = fminf(mn, d);
    }
    float a = sca[c];
    float v = a * (a >= 0.f ? mx : mn) + shb[c];
    out[((size_t)b * M + m) * 64 + c] = v >= 0.f ? v : 0.2f * v;
}

// ====== gather pool with bn+lrelu from scsh (min/max trick) ============
__global__ void pool_bn_kernel(const float* __restrict__ f, const int* __restrict__ idx,
                               float* __restrict__ out, int M, int Nf, int C,
                               int out_stride, int out_off, const float* __restrict__ scsh) {
    int c = threadIdx.x;                               // blockDim.x == C
    int m = blockIdx.x * blockDim.y + threadIdx.y;
    int b = blockIdx.y;
    const int* ip = idx + ((size_t)b * M + m) * KNN;
    const float* fb = f + (size_t)b * Nf * C;
    float mx = -3.4e38f, mn = 3.4e38f;
#pragma unroll
    for (int k = 0; k < KNN; ++k) {
        int j = ip[k];
        float v = fb[(size_t)j * C + c];
        mx = fmaxf(mx, v);
        mn = fminf(mn, v);
    }
    float a = scsh[c];
    float v = a * (a >= 0.f ? mx : mn) + scsh[C + c];
    v = v >= 0.f ? v : 0.2f * v;
    out[((size_t)b * M + m) * out_stride + out_off + c] = v;
}

// ===== GEMM: BM x 64 tile, float4 staging, BN-stats epilogue, merged pool ====
template <int BM, bool POOL>
__global__ void gemm_kernel(const float* __restrict__ A, const float* __restrict__ W,
                            float* __restrict__ Cout, int M, int N, int K,
                            float* __restrict__ part /*[M/BM][2][N]*/, int nbn,
                            const float* __restrict__ pf, const int* __restrict__ pidx,
                            float* __restrict__ pout, int pNf, int pC, int pstride, int poff) {
    constexpr int RM = BM / 16;
    int t = threadIdx.x;
    int nbm = M / BM;
    int bx = blockIdx.x;
    if (POOL && bx >= nbm * nbn) {
        int e = bx - nbm * nbn;
        int rows = 256 / pC;
        int bpb = 64 / rows;
        int b = e / bpb, mi = e % bpb;
        int m = mi * rows + t / pC;
        int c = t % pC;
        const int* ip = pidx + ((size_t)b * 64 + m) * KNN;
        const float* fb = pf + (size_t)b * pNf * pC;
        float mx = -3.4e38f;
#pragma unroll
        for (int k = 0; k < KNN; ++k) mx = fmaxf(mx, fb[(size_t)ip[k] * pC + c]);
        pout[((size_t)b * 64 + m) * pstride + poff + c] = mx;
        return;
    }
    int bm = bx / nbn, bn = bx % nbn;
    __shared__ float As[16][BM + 4], Ws[16][68];
    int tx = t & 15, ty = t >> 4;
    const float* Ab = A + (size_t)bm * BM * K;
    const float* Wb = W + (size_t)bn * 64 * K;
    float acc[RM][4] = {};
    int srow = t >> 2, skb = (t & 3) << 2;
    for (int k0 = 0; k0 < K; k0 += 16) {
        if (t < BM * 4) {
            float4 av = *(const float4*)&Ab[(size_t)srow * K + k0 + skb];
            As[skb][srow] = av.x; As[skb + 1][srow] = av.y;
            As[skb + 2][srow] = av.z; As[skb + 3][srow] = av.w;
        }
        {
            float4 wv = *(const float4*)&Wb[(size_t)srow * K + k0 + skb];
            Ws[skb][srow] = wv.x; Ws[skb + 1][srow] = wv.y;
            Ws[skb + 2][srow] = wv.z; Ws[skb + 3][srow] = wv.w;
        }
        __syncthreads();
#pragma unroll
        for (int kk = 0; kk < 16; ++kk) {
            float av[RM];
#pragma unroll
            for (int i = 0; i < RM; ++i) av[i] = As[kk][ty * RM + i];
            float4 w4 = *(const float4*)&Ws[kk][tx * 4];
            float wv[4] = {w4.x, w4.y, w4.z, w4.w};
#pragma unroll
            for (int i = 0; i < RM; ++i)
#pragma unroll
                for (int j = 0; j < 4; ++j) acc[i][j] += av[i] * wv[j];
        }
        __syncthreads();
    }
#pragma unroll
    for (int i = 0; i < RM; ++i) {
        float4 v = make_float4(acc[i][0], acc[i][1], acc[i][2], acc[i][3]);
        *(float4*)&Cout[(size_t)(bm * BM + ty * RM + i) * N + bn * 64 + tx * 4] = v;
    }
    __shared__ float2 sred[16][64];
#pragma unroll
    for (int j = 0; j < 4; ++j) {
        float s = 0.f, q = 0.f;
#pragma unroll
        for (int i = 0; i < RM; ++i) { s += acc[i][j]; q += acc[i][j] * acc[i][j]; }
        sred[ty][tx * 4 + j] = make_float2(s, q);
    }
    __syncthreads();
    if (t < 64) {
        float s = 0.f, q = 0.f;
#pragma unroll
        for (int r = 0; r < 16; ++r) { s += sred[r][t].x; q += sred[r][t].y; }
        part[(size_t)bm * 2 * N + bn * 64 + t] = s;
        part[(size_t)bm * 2 * N + N + bn * 64 + t] = q;
    }
}

// partials -> scale/shift
__global__ void bn_finalize_kernel(const float* __restrict__ part, int nparts, int C, int R,
                                   const float* __restrict__ g, const float* __restrict__ bb,
                                   float* __restrict__ scsh) {
    int c = blockIdx.x;
    int t = threadIdx.x;   // 256
    float s = 0.f, q = 0.f;
    for (int k = t; k < nparts; k += 256) {
        s += part[(size_t)k * 2 * C + c];
        q += part[(size_t)k * 2 * C + C + c];
    }
#pragma unroll
    for (int o = 32; o; o >>= 1) { s += __shfl_down(s, o); q += __shfl_down(q, o); }
    __shared__ float2 red[4];
    if ((t & 63) == 0) red[t >> 6] = make_float2(s, q);
    __syncthreads();
    if (t == 0) {
        s = red[0].x + red[1].x + red[2].x + red[3].x;
        q = red[0].y + red[1].y + red[2].y + red[3].y;
        float mean = s / (float)R;
        float var = q / (float)R - mean * mean;
        float a = g[c] * rsqrtf(var + BN_EPS);
        scsh[c] = a;
        scsh[C + c] = bb[c] - mean * a;
    }
}

// ============ global max+mean pool with fused bn+lrelu ============
__global__ void global_pool_bn_kernel(const float* __restrict__ h,
                                      const float* __restrict__ scsh,
                                      float* __restrict__ out) {
    int c = blockIdx.x * 256 + threadIdx.x;   // C=1024
    int b = blockIdx.y;
    const float* hb = h + (size_t)b * 64 * 1024;
    float a = scsh[c], sh = scsh[1024 + c];
    float mx = -3.4e38f, s = 0.f;
    for (int r = 0; r < 64; ++r) {
        float v = a * hb[r * 1024 + c] + sh;
        v = v >= 0.f ? v : 0.2f * v;
        mx = fmaxf(mx, v); s += v;
    }
    out[b * 2048 + c] = mx;
    out[b * 2048 + 1024 + c] = s * (1.f / 64.f);
}

// ==== head1: out[m,n] = A[m,:] . W[n,:]  (K=2048), 8-way K-split + LDS red ===
__global__ void head_gemm_wide(const float* __restrict__ A, const float* __restrict__ W,
                               float* __restrict__ out, int N, int K) {
    __shared__ float red[8][32];
    int t = threadIdx.x;     // 256
    int m = blockIdx.y;
    int nl = t & 31, kq = t >> 5;   // 8 K-chunks
    int n = blockIdx.x * 32 + nl;
    int Kc = K >> 3;
    const float4* a4 = (const float4*)(A + (size_t)m * K + kq * Kc);
    const float4* w4 = (const float4*)(W + (size_t)n * K + kq * Kc);
    float s = 0.f;
    for (int k = 0; k < (Kc >> 2); ++k) {
        float4 a = a4[k], w = w4[k];
        s += a.x * w.x + a.y * w.y + a.z * w.z + a.w * w.w;
    }
    red[kq][nl] = s;
    __syncthreads();
    if (t < 32) {
        float r = 0.f;
#pragma unroll
        for (int i = 0; i < 8; ++i) r += red[i][t];
        out[(size_t)m * N + blockIdx.x * 32 + t] = r;
    }
}

// ==== head2: h7pre[m,n] = (bn_lrelu(h6pre))[m,:] . l2w[n,:] + l2b  (K=512) ====
__global__ void head_bn_gemm2(const float* __restrict__ Apre,
                              const float* __restrict__ g, const float* __restrict__ bb,
                              const float* __restrict__ W, const float* __restrict__ bias,
                              float* __restrict__ out) {
    __shared__ float An[512];
    __shared__ float red[4][64];
    int t = threadIdx.x;     // 256
    int m = blockIdx.y;
    for (int c = t; c < 512; c += 256) {
        float s = 0.f, q = 0.f, vm = 0.f;
#pragma unroll
        for (int r = 0; r < 16; ++r) {
            float v = Apre[r * 512 + c];
            s += v; q += v * v;
            if (r == m) vm = v;
        }
        float mean = s * (1.f / 16.f);
        float var = q * (1.f / 16.f) - mean * mean;
        float a = g[c] * rsqrtf(var + BN_EPS);
        float v = a * (vm - mean) + bb[c];
        An[c] = v >= 0.f ? v : 0.2f * v;
    }
    __syncthreads();
    int nl = t & 63, kq = t >> 6;
    int n = blockIdx.x * 64 + nl;
    const float* wn = W + (size_t)n * 512 + kq * 128;
    const float* an = An + kq * 128;
    float s = 0.f;
    for (int k = 0; k < 128; k += 4) {
        float4 a4 = *(const float4*)&an[k];
        float4 w4 = *(const float4*)&wn[k];
        s += a4.x * w4.x + a4.y * w4.y + a4.z * w4.z + a4.w * w4.w;
    }
    red[kq][nl] = s;
    __syncthreads();
    if (t < 64) {
        float r = red[0][t] + red[1][t] + red[2][t] + red[3][t];
        out[(size_t)m * 256 + blockIdx.x * 64 + t] = r + bias[blockIdx.x * 64 + t];
    }
}

// ==== head3: out[m,n] = (bn_lrelu(h7pre))[m,:] . l3w[n,:] + l3b (K=256,N=40) ==
__global__ void head_bn_gemm3(const float* __restrict__ Apre,
                              const float* __restrict__ g, const float* __restrict__ bb,
                              const float* __restrict__ W, const float* __restrict__ bias,
                              float* __restrict__ out) {
    __shared__ float An[256];
    __shared__ float red[4][64];
    int t = threadIdx.x;     // 256
    int m = blockIdx.x;
    {
        int c = t;
        float s = 0.f, q = 0.f, vm = 0.f;
#pragma unroll
        for (int r = 0; r < 16; ++r) {
            float v = Apre[r * 256 + c];
            s += v; q += v * v;
            if (r == m) vm = v;
        }
        float mean = s * (1.f / 16.f);
        float var = q * (1.f / 16.f) - mean * mean;
        float a = g[c] * rsqrtf(var + BN_EPS);
        float v = a * (vm - mean) + bb[c];
        An[c] = v >= 0.f ? v : 0.2f * v;
    }
    __syncthreads();
    int nl = t & 63, kq = t >> 6;
    float s = 0.f;
    if (nl < 40) {
        const float* wn = W + (size_t)nl * 256 + kq * 64;
        const float* an = An + kq * 64;
        for (int k = 0; k < 64; k += 4) {
            float4 a4 = *(const float4*)&an[k];
            float4 w4 = *(const float4*)&wn[k];
            s += a4.x * w4.x + a4.y * w4.y + a4.z * w4.z + a4.w * w4.w;
        }
    }
    red[kq][nl] = s;
    __syncthreads();
    if (t < 40) {
        float r = red[0][t] + red[1][t] + red[2][t] + red[3][t];
        out[(size_t)m * 40 + t] = r + bias[t];
    }
}

extern "C" void kernel_launch(void* const* d_in, const int* in_sizes, int n_in,
                              void* d_out, int out_size, void* d_ws, size_t ws_size,
                              hipStream_t stream) {
    const int B = 16, N = 4096;
    const float* x   = (const float*)d_in[0];
    const float* w1  = (const float*)d_in[1];
    const float* g1  = (const float*)d_in[2];
    const float* b1  = (const float*)d_in[3];
    const float* w2  = (const float*)d_in[4];
    const float* g2  = (const float*)d_in[5];
    const float* b2  = (const float*)d_in[6];
    const float* w3  = (const float*)d_in[7];
    const float* g3  = (const float*)d_in[8];
    const float* b3  = (const float*)d_in[9];
    const float* w4  = (const float*)d_in[10];
    const float* g4  = (const float*)d_in[11];
    const float* b4  = (const float*)d_in[12];
    const float* w5  = (const float*)d_in[13];
    const float* g5  = (const float*)d_in[14];
    const float* b5  = (const float*)d_in[15];
    const float* l1w = (const float*)d_in[16];
    const float* g6  = (const float*)d_in[17];
    const float* b6  = (const float*)d_in[18];
    const float* l2w = (const float*)d_in[19];
    const float* l2b = (const float*)d_in[20];
    const float* g7  = (const float*)d_in[21];
    const float* b7  = (const float*)d_in[22];
    const float* l3w = (const float*)d_in[23];
    const float* l3b = (const float*)d_in[24];
    float* outp = (float*)d_out;

    char* ws = (char*)d_ws;
    size_t off = 0;
    auto alloc = [&](size_t bytes) -> void* {
        void* p = ws + off;
        off += (bytes + 255) & ~(size_t)255;
        return p;
    };
    float* f1p   = (float*)alloc((size_t)B * 1024 * 64 * 4);
    float* f2pre = (float*)alloc((size_t)B * 1024 * 64 * 4);
    float* f2p   = (float*)alloc((size_t)B * 256 * 64 * 4);
    float* f3pre = (float*)alloc((size_t)B * 256 * 128 * 4);
    float* f3p   = (float*)alloc((size_t)B * 128 * 128 * 4);
    float* f4pre = (float*)alloc((size_t)B * 128 * 256 * 4);
    float* hcat  = (float*)alloc((size_t)B * 64 * 512 * 4);
    float* h5pre = (float*)alloc((size_t)B * 64 * 1024 * 4);
    float* hg    = (float*)alloc((size_t)B * 2048 * 4);
    float* h6pre = (float*)alloc((size_t)B * 512 * 4);
    float* h7pre = (float*)alloc((size_t)B * 256 * 4);
    int* idxA = (int*)alloc((size_t)B * 1024 * KNN * 4);
    int* idxB = (int*)alloc((size_t)B * 64 * KNN * 4);
    int* idxC = (int*)alloc((size_t)B * 256 * KNN * 4);
    int* idxD = (int*)alloc((size_t)B * 64 * KNN * 4);
    int* idxE = (int*)alloc((size_t)B * 128 * KNN * 4);
    int* idxF = (int*)alloc((size_t)B * 64 * KNN * 4);
    float* mom   = (float*)alloc((size_t)B * 4 * 9 * 4);
    float4* pkbuf = (float4*)alloc((size_t)B * N * 16);
    float* part2 = (float*)alloc((size_t)512 * 2 * 64 * 4);
    float* part3 = (float*)alloc((size_t)128 * 2 * 128 * 4);
    float* part4 = (float*)alloc((size_t)64 * 2 * 256 * 4);
    float* part5 = (float*)alloc((size_t)32 * 2 * 1024 * 4);
    float* sc2 = (float*)alloc(2 * 64 * 4);
    float* sc3 = (float*)alloc(2 * 128 * 4);
    float* sc4 = (float*)alloc(2 * 256 * 4);
    float* sc5 = (float*)alloc(2 * 1024 * 4);

    // ---- moments + packed points, then KNN (all 6 tasks, lean)
    moments3_kernel<<<dim3(B, 4), 256, 0, stream>>>(x, N, mom, pkbuf);
    knn_all_kernel<<<dim3(200, B), 256, 0, stream>>>(pkbuf, N, idxA, idxB, idxC, idxD, idxE, idxF);

    // ---- stage 1 pool (standalone; cheap, keeps knn lean)
    pool1_kernel<<<dim3(256, B), dim3(64, 4), 0, stream>>>(pkbuf, N, idxA, w1, mom, g1, b1,
                                                           1.f / (B * N), B * 4, f1p, 1024);

    // ---- stage 2: gemm (512 blocks) + merged pool B (256 blocks)
    gemm_kernel<32, true><<<dim3(512 + 256), 256, 0, stream>>>(
        f1p, w2, f2pre, B * 1024, 64, 64, part2, 1,
        f1p, idxB, hcat, 1024, 64, 512, 0);
    bn_finalize_kernel<<<dim3(64), 256, 0, stream>>>(part2, 512, 64, B * 1024, g2, b2, sc2);
    pool_bn_kernel<<<dim3(64, B), dim3(64, 4), 0, stream>>>(f2pre, idxC, f2p, 256, 1024, 64, 64, 0, sc2);

    // ---- stage 3: gemm (256 blocks) + merged pool D (256 blocks)
    gemm_kernel<32, true><<<dim3(256 + 256), 256, 0, stream>>>(
        f2p, w3, f3pre, B * 256, 128, 64, part3, 2,
        f2p, idxD, hcat, 256, 64, 512, 64);
    bn_finalize_kernel<<<dim3(128), 256, 0, stream>>>(part3, 128, 128, B * 256, g3, b3, sc3);
    pool_bn_kernel<<<dim3(64, B), dim3(128, 2), 0, stream>>>(f3pre, idxE, f3p, 128, 256, 128, 128, 0, sc3);

    // ---- stage 4: gemm (256 blocks) + merged pool F (512 blocks)
    gemm_kernel<32, true><<<dim3(256 + 512), 256, 0, stream>>>(
        f3p, w4, f4pre, B * 128, 256, 128, part4, 4,
        f3p, idxF, hcat, 128, 128, 512, 128);
    bn_finalize_kernel<<<dim3(256), 256, 0, stream>>>(part4, 64, 256, B * 128, g4, b4, sc4);
    pool_bn_kernel<<<dim3(64, B), dim3(256, 1), 0, stream>>>(f4pre, idxF, hcat, 64, 128, 256, 512, 256, sc4);

    // ---- stage 5
    gemm_kernel<32, false><<<dim3(512), 256, 0, stream>>>(
        hcat, w5, h5pre, B * 64, 1024, 512, part5, 16,
        nullptr, nullptr, nullptr, 0, 1, 0, 0);
    bn_finalize_kernel<<<dim3(1024), 256, 0, stream>>>(part5, 32, 1024, B * 64, g5, b5, sc5);
    global_pool_bn_kernel<<<dim3(4, B), 256, 0, stream>>>(h5pre, sc5, hg);

    // ---- head
    head_gemm_wide<<<dim3(16, B), 256, 0, stream>>>(hg, l1w, h6pre, 512, 2048);
    head_bn_gemm2<<<dim3(4, B), 256, 0, stream>>>(h6pre, g6, b6, l2w, l2b, h7pre);
    head_bn_gemm3<<<dim3(B), 256, 0, stream>>>(h7pre, g7, b7, l3w, l3b, outp);
}